// Round 6
// baseline (1725.525 us; speedup 1.0000x reference)
//
#include <hip/hip_runtime.h>
#include <cstdint>
#include <cstddef>
#include <cmath>

#define H  2048
#define BB 2048   // batch
#define TT 64     // time steps
#define NC 10     // classes

typedef __bf16 bf16;
typedef bf16  bf16x8 __attribute__((ext_vector_type(8)));
typedef float f32x4  __attribute__((ext_vector_type(4)));

// ---------------------------------------------------------------------------
// async global->LDS, 16B per lane. LDS dest is wave-uniform base + lane*16;
// global source is per-lane.
// ---------------------------------------------------------------------------
__device__ __forceinline__ void load_lds16(const void* g, void* l) {
    __builtin_amdgcn_global_load_lds(
        (__attribute__((address_space(1))) void*)(void*)g,
        (__attribute__((address_space(3))) void*)l,
        16, 0, 0);
}

// ---------------------------------------------------------------------------
// FRAG-MAJOR layout (W_hh and S, since R12).
// For a matrix [R rows][H k-cols] (bf16):
//   subtile (r16, k32) = 16 rows x 32 k = 1024 B at id = r16*(H/32) + k32.
//   lane-slot l (16 B) holds M[r16*16 + (l&15)][k32*32 + (l>>4)*8 .. +8]
// = exactly the v_mfma_f32_16x16x32_bf16 A/B fragment, so a wave's frag load
// is ONE coalesced 1 KB segment: base + id*512 + lane*8 (bf16 elems).
// ---------------------------------------------------------------------------
__global__ void w_shuffle_kernel(const float* __restrict__ Whh,
                                 bf16* __restrict__ Wshuf) {
    int tid = blockIdx.x * blockDim.x + threadIdx.x;   // 0 .. H*H/8-1
    int sub = tid >> 6;          // subtile id
    int l   = tid & 63;          // dest lane slot
    int n16 = sub >> 6;          // 0..127
    int k32 = sub & 63;          // 0..63
    int n = n16 * 16 + (l & 15);
    int k = k32 * 32 + (l >> 4) * 8;
    const float* src = Whh + (size_t)n * H + k;
    bf16x8 o;
#pragma unroll
    for (int j = 0; j < 8; ++j) o[j] = (bf16)src[j];
    *(bf16x8*)(Wshuf + (size_t)tid * 8) = o;
}

// ---------------------------------------------------------------------------
// t = 0: S[b,i] = tanh(Whx[i]*x[b,0] + bh[i]), written FRAG-MAJOR.
// ---------------------------------------------------------------------------
__global__ void rnn_init(const float* __restrict__ x,     // [B, T]
                         const float* __restrict__ Whx,   // [H]
                         const float* __restrict__ bh,    // [H]
                         bf16* __restrict__ S) {          // frag-major
    int b  = blockIdx.x;
    int i0 = threadIdx.x * 8;
    float xv = x[(size_t)b * TT];
    bf16x8 o;
#pragma unroll
    for (int j = 0; j < 8; ++j)
        o[j] = (bf16)tanhf(Whx[i0 + j] * xv + bh[i0 + j]);
    size_t sub  = (size_t)(b >> 4) * 64 + (i0 >> 5);
    size_t slot = (size_t)(b & 15) | (size_t)(((i0 >> 3) & 3) << 4);
    *(bf16x8*)(S + (sub * 64 + slot) * 8) = o;
}

// ---------------------------------------------------------------------------
// One RNN time step, Round-16 "64x64 wave tiles: halve LDS amplification":
//   Sw[b,i] = tanh( sum_k Sr[b,k]*W[i,k] + Whx[i]*x[b,t] + bh[i] )
//
// R15 post-mortem: LDS traffic is the wall. 8 waves x 32x64 tiles read
// (2 A + 4 B) KB per k32 per wave = 3x read amplification -> 128 KB/phase
// (1143 cy) vs MFMA 620 cy; step floor 15.3 us, observed 23.7.
//
// Fix: 4 waves x 64x64 tiles (M_f=N_f=4 minimizes M_f+N_f at M_f*N_f=16).
// Per-wave reads 8 KB/k32 for 16 MFMAs -> amplification 2x. Per phase:
// 64 KB reads + 32 KB writes = 96 KB (857 cy) ~ MFMA (620 cy). Everything
// else inherits the R15 skeleton unchanged:
//   - frag-major S and W (1 KB coalesced wave segments)
//   - XCD-owns-n (W panel 1 MB L2-resident across all 63 steps)
//   - 4-slot LDS ring (4 x 32 KB), counted vmcnt NEVER 0 in-loop
//     (steady vmcnt(16) = 2 younger phases x 8 ops in flight), raw
//     s_barrier (no drain), 3-phase-deep prefetch, setprio on MFMA.
//   - accumulation: each acc cell sums the same 64 k32-chunks in the same
//     order as R15 -> bit-identical numerics.
// Known risk: 1 wave/SIMD (no TLP); phase-start lgkm bubble (~200 cy)
// exposed. If this regresses, next step is 8-wave split-K.
// ---------------------------------------------------------------------------
#define PH_WAIT(NSTR) asm volatile("s_waitcnt vmcnt(" NSTR ")" ::: "memory")
#define SBAR0()       __builtin_amdgcn_sched_barrier(0)

__launch_bounds__(256, 1)
__global__ void rnn_step(const float* __restrict__ x,     // [B, T]
                         const float* __restrict__ Whx,   // [H]
                         const float* __restrict__ bh,    // [H]
                         const bf16*  __restrict__ Wshuf, // frag-major W_hh
                         const bf16*  __restrict__ Sr,    // frag-major S read
                         bf16* __restrict__ Sw,           // frag-major S write
                         int t) {
    // ring slot = 32 segs x 1 KB: segs [j*16 + 0..7]  = A m16 0..7 (chunk j),
    //                             segs [j*16 + 8..15] = B n16 0..7 (chunk j)
    __shared__ __align__(16) char Ls[4][32768];   // 128 KB -> 1 block/CU

    const int tid  = threadIdx.x;
    const int w    = tid >> 6;          // wave 0..3
    const int lane = tid & 63;
    const int lrow = lane & 15;
    const int quad = lane >> 4;

    // XCD-owns-n mapping: XCD x covers n-cols [x*256, x*256+256).
    const int xcd = blockIdx.x & 7;
    const int loc = blockIdx.x >> 3;               // 0..31
    const int bm0 = (loc >> 1) * 128;              // batch-row tile origin
    const int bn0 = xcd * 256 + (loc & 1) * 128;   // hidden-col tile origin

    const int qm   = w & 1;                        // 2 m-groups x 64 rows
    const int qn   = w >> 1;                       // 2 n-groups x 64 cols
    const int m16w = (bm0 >> 4) + qm * 4;          // wave's first m16 subtile
    const int cn0  = bn0 + qn * 64;                // wave's first col

    // staging sources (per wave): wave w owns A m16 subtiles {2w, 2w+1} and
    // B n16 subtiles {2w, 2w+1}; 1 KB contiguous per k32, per-lane +lane*16B.
    const char* srcA = (const char*)Sr +
        ((size_t)((bm0 >> 4) + 2 * w) * 64) * 1024 + (size_t)lane * 16;
    const char* srcB = (const char*)Wshuf +
        ((size_t)((bn0 >> 4) + 2 * w) * 64) * 1024 + (size_t)lane * 16;

    f32x4 acc[4][4];
#pragma unroll
    for (int i = 0; i < 4; ++i)
#pragma unroll
        for (int j = 0; j < 4; ++j) acc[i][j] = (f32x4){0.f, 0.f, 0.f, 0.f};

    // ---- issue section for phase pp into ring slot RI (8 VMEM ops) ----
#define ISSUE(RI, pp)                                                        \
    {                                                                        \
        _Pragma("unroll")                                                    \
        for (int j = 0; j < 2; ++j) {                                        \
            _Pragma("unroll")                                                \
            for (int u = 0; u < 2; ++u) {                                    \
                load_lds16(srcA + ((size_t)u * 64 + 2 * (pp) + j) * 1024,    \
                           &Ls[RI][(j * 16 + 2 * w + u) * 1024]);            \
                load_lds16(srcB + ((size_t)u * 64 + 2 * (pp) + j) * 1024,    \
                           &Ls[RI][(j * 16 + 8 + 2 * w + u) * 1024]);        \
            }                                                                \
        }                                                                    \
    }

    // ---- compute section for phase p using ring slot RI (32 MFMA) ----
#define COMPUTE(RI)                                                          \
    {                                                                        \
        _Pragma("unroll")                                                    \
        for (int j = 0; j < 2; ++j) {                                        \
            bf16x8 Af[4], Bf[4];                                             \
            _Pragma("unroll")                                                \
            for (int fm = 0; fm < 4; ++fm)                                   \
                Af[fm] = *(const bf16x8*)&Ls[RI]                             \
                    [(j * 16 + qm * 4 + fm) * 1024 + lane * 16];             \
            _Pragma("unroll")                                                \
            for (int fn = 0; fn < 4; ++fn)                                   \
                Bf[fn] = *(const bf16x8*)&Ls[RI]                             \
                    [(j * 16 + 8 + qn * 4 + fn) * 1024 + lane * 16];         \
            __builtin_amdgcn_s_setprio(1);                                   \
            _Pragma("unroll")                                                \
            for (int fm = 0; fm < 4; ++fm)                                   \
                _Pragma("unroll")                                            \
                for (int fn = 0; fn < 4; ++fn)                               \
                    acc[fm][fn] = __builtin_amdgcn_mfma_f32_16x16x32_bf16(   \
                        Af[fm], Bf[fn], acc[fm][fn], 0, 0, 0);               \
            __builtin_amdgcn_s_setprio(0);                                   \
        }                                                                    \
    }

#define PHASE(RI, RN, p, WNSTR, DOISS)                                       \
    {                                                                        \
        PH_WAIT(WNSTR);                                                      \
        SBAR0();                                                             \
        __builtin_amdgcn_s_barrier();                                        \
        SBAR0();                                                             \
        if (DOISS) ISSUE(RN, (p) + 3);                                       \
        SBAR0();                                                             \
        COMPUTE(RI);                                                         \
    }

    // prologue: issue phases 0,1,2 into slots 0,1,2 (order pinned)
    ISSUE(0, 0); SBAR0();
    ISSUE(1, 1); SBAR0();
    ISSUE(2, 2); SBAR0();

    // main loop: phases 0..27 (7 macro-iters x 4), steady wait = 16
#pragma unroll 1
    for (int q = 0; q < 7; ++q) {
        int p = 4 * q;
        PHASE(0, 3, p + 0, "16", true);
        PHASE(1, 0, p + 1, "16", true);
        PHASE(2, 1, p + 2, "16", true);
        PHASE(3, 2, p + 3, "16", true);
    }
    // peeled tail: phases 28..31
    PHASE(0, 3, 28, "16", true);    // issues phase 31
    PHASE(1, 0, 29, "16", false);
    PHASE(2, 1, 30, "8",  false);
    PHASE(3, 2, 31, "0",  false);

#undef PHASE
#undef COMPUTE
#undef ISSUE

    // ---- epilogue: z += Whx*x + bh; tanh; transpose to frag-major Sw ----
    // acc layout (16x16x32): col = lane&15, row = quad*4 + reg [m89-verified]
    // Wave-private 64 rows x 128 B region in slot 0 (bytes w*8K..w*8K+8K);
    // stragglers still computing phase 31 read slot 3 -> disjoint. The
    // transpose write/read is same-wave -> lgkmcnt ordering suffices, no
    // __syncthreads needed.
    bf16* Lw = (bf16*)&Ls[0][0] + (size_t)w * 4096;  // 64 rows x 128 B, swz
#pragma unroll
    for (int fm = 0; fm < 4; ++fm) {
        int rb = bm0 + qm * 64 + fm * 16 + quad * 4;
        float xv[4];
#pragma unroll
        for (int r = 0; r < 4; ++r) xv[r] = x[(size_t)(rb + r) * TT + t];
#pragma unroll
        for (int fn = 0; fn < 4; ++fn) {
            int col = cn0 + fn * 16 + lrow;
            float wx = Whx[col], bb = bh[col];
            int cbyte = (fn * 16 + lrow) * 2;
#pragma unroll
            for (int r = 0; r < 4; ++r) {
                int row_l = fm * 16 + quad * 4 + r;
                float z = acc[fm][fn][r] + wx * xv[r] + bb;
                *(bf16*)((char*)Lw + row_l * 128 +
                         (cbyte ^ ((row_l & 7) << 4))) = (bf16)tanhf(z);
            }
        }
    }
    // read own wave's tile in frag-slot order; 16B coalesced global stores.
#pragma unroll
    for (int fm = 0; fm < 4; ++fm) {
#pragma unroll
        for (int kc = 0; kc < 2; ++kc) {
            int row_l = fm * 16 + lrow;
            int cb    = (kc * 64 + quad * 16) ^ ((row_l & 7) << 4);
            bf16x8 v = *(const bf16x8*)((const char*)Lw + row_l * 128 + cb);
            size_t sub = (size_t)(m16w + fm) * 64 + (cn0 >> 5) + kc;
            *(bf16x8*)(Sw + (sub * 64 + lane) * 8) = v;
        }
    }
}

// ---------------------------------------------------------------------------
// out[b,c] = sum_h Why[h,c] * S[b,h] + bp[c]   (S frag-major)
// ---------------------------------------------------------------------------
__global__ void out_proj(const bf16* __restrict__ S,
                         const float* __restrict__ Why,   // [H, C]
                         const float* __restrict__ bp,    // [C]
                         float* __restrict__ out) {       // [B, C]
    int b = blockIdx.x, tid = threadIdx.x;
    int h0 = tid * 8;                                     // 256*8 = H exactly
    size_t sub  = (size_t)(b >> 4) * 64 + (h0 >> 5);
    size_t slot = (size_t)(b & 15) | (size_t)(((h0 >> 3) & 3) << 4);
    bf16x8 v = *(const bf16x8*)(S + (sub * 64 + slot) * 8);
    float p[NC];
#pragma unroll
    for (int c = 0; c < NC; ++c) p[c] = 0.f;
#pragma unroll
    for (int j = 0; j < 8; ++j) {
        float s = (float)v[j];
        const float* wr = Why + (size_t)(h0 + j) * NC;
#pragma unroll
        for (int c = 0; c < NC; ++c) p[c] += s * wr[c];
    }
    __shared__ float red[256 * NC];
#pragma unroll
    for (int c = 0; c < NC; ++c) red[tid * NC + c] = p[c];
    __syncthreads();
    for (int s = 128; s > 0; s >>= 1) {
        if (tid < s)
#pragma unroll
            for (int c = 0; c < NC; ++c) red[tid * NC + c] += red[(tid + s) * NC + c];
        __syncthreads();
    }
    if (tid < NC) out[(size_t)b * NC + tid] = red[tid] + bp[tid];
}

// ---------------------------------------------------------------------------
extern "C" void kernel_launch(void* const* d_in, const int* in_sizes, int n_in,
                              void* d_out, int out_size, void* d_ws, size_t ws_size,
                              hipStream_t stream) {
    const float* x   = (const float*)d_in[0];   // [B, T]
    const float* Whx = (const float*)d_in[1];   // [H, 1]
    const float* Whh = (const float*)d_in[2];   // [H, H]
    const float* Why = (const float*)d_in[3];   // [H, C]
    const float* bh  = (const float*)d_in[4];   // [H, 1]
    const float* bp  = (const float*)d_in[5];   // [C, 1]
    float* out = (float*)d_out;

    // workspace: Wshuf (8 MB) | S0 (8 MB) | S1 (8 MB)   (all frag-major)
    bf16* Wshuf = (bf16*)d_ws;
    bf16* S0 = (bf16*)((char*)d_ws + (size_t)8 * 1024 * 1024);
    bf16* S1 = (bf16*)((char*)d_ws + (size_t)16 * 1024 * 1024);

    hipLaunchKernelGGL(w_shuffle_kernel, dim3((H * H / 8) / 256), dim3(256),
                       0, stream, Whh, Wshuf);

    // t = 0 writes S1; step t reads (t&1 ? S1 : S0), writes the other.
    hipLaunchKernelGGL(rnn_init, dim3(BB), dim3(256), 0, stream, x, Whx, bh, S1);

    for (int t = 1; t < TT; ++t) {
        const bf16* Srd = (t & 1) ? S1 : S0;
        bf16*       Swr = (t & 1) ? S0 : S1;
        hipLaunchKernelGGL(rnn_step, dim3(256), dim3(256), 0, stream,
                           x, Whx, bh, Wshuf, Srd, Swr, t);
    }

    // t=63 (odd) wrote S0
    hipLaunchKernelGGL(out_proj, dim3(BB), dim3(256), 0, stream, S0, Why, bp, out);
}